// Round 4
// baseline (194.429 us; speedup 1.0000x reference)
//
#include <hip/hip_runtime.h>
#include <math.h>

#define TT 20
#define NCLS 80
#define MAXPOS 32   // positives per block <= targets per batch (20)

__device__ __forceinline__ float sigmoidf_(float z) {
    return 1.0f / (1.0f + expf(-z));
}

// torch BCELoss(reduction='none') on probabilities with log clamped at -100
__device__ __forceinline__ float bce_(float p, float t) {
    float logp   = fmaxf(logf(p), -100.0f);
    float log1mp = fmaxf(log1pf(-p), -100.0f);
    return -(t * logp + (1.0f - t) * log1mp);
}

// Single dispatch: all 3 levels * bs batches + fused final reduction (last-block-done).
// Block layout per batch: level0 (13x13): 2 blocks, level1 (26x26): 8, level2 (52x52): 32.
__global__ __launch_bounds__(256) void yolo_fused_kernel(
    const float* __restrict__ x0, const float* __restrict__ x1, const float* __restrict__ x2,
    const float* __restrict__ gtb, const int* __restrict__ gtl,
    float* __restrict__ partials, int* __restrict__ counter,
    float* __restrict__ out, int bs, int nblocks, float inv_bs)
{
    const int tid = threadIdx.x;
    const int blk = blockIdx.x;
    const int t0 = 2 * bs, t1 = t0 + 8 * bs;

    int level, b, chunk, W;
    const float* __restrict__ xp;
    float inv_stride;
    if (blk < t0)      { level = 0; b = blk >> 1;        chunk = blk & 1;         xp = x0; W = 13; inv_stride = 1.0f / 32.0f; }
    else if (blk < t1) { level = 1; int r = blk - t0; b = r >> 3; chunk = r & 7;  xp = x1; W = 26; inv_stride = 1.0f / 16.0f; }
    else               { level = 2; int r = blk - t1; b = r >> 5; chunk = r & 31; xp = x2; W = 52; inv_stride = 1.0f / 8.0f;  }
    const int H = W, HW = W * W, cells = 3 * HW;

    float a0x = ((level == 0) ? 116.f : (level == 1) ? 30.f : 10.f) * inv_stride;
    float a0y = ((level == 0) ?  90.f : (level == 1) ? 61.f : 13.f) * inv_stride;
    float a1x = ((level == 0) ? 156.f : (level == 1) ? 62.f : 16.f) * inv_stride;
    float a1y = ((level == 0) ? 198.f : (level == 1) ? 45.f : 30.f) * inv_stride;
    float a2x = ((level == 0) ? 373.f : (level == 1) ? 59.f : 33.f) * inv_stride;
    float a2y = ((level == 0) ? 326.f : (level == 1) ? 119.f: 23.f) * inv_stride;

    __shared__ float s_tb[TT][4];
    __shared__ float s_area[TT];
    __shared__ float s_txy[TT][2];
    __shared__ float s_twh[TT][2];
    __shared__ int   s_flat[TT];
    __shared__ int   s_valid[TT];
    __shared__ int   s_label[TT];
    __shared__ int   s_npos;
    __shared__ int   s_last;
    __shared__ int   s_poff[MAXPOS];
    __shared__ unsigned int s_pm0[MAXPOS], s_pm1[MAXPOS], s_pm2[MAXPOS];

    // ---- prefetch this thread's 5 channel values FIRST so the cold-HBM
    //      latency overlaps the target-prep phase and the barrier ----
    const int n = chunk * 256 + tid;
    const bool active = n < cells;
    int a = 0, rem = 0, ci = 0, cj = 0, off_cell = 0;
    float z0 = 0.f, z1 = 0.f, z2 = 0.f, z3 = 0.f, z4 = 0.f;
    if (active) {
        a   = n / HW;
        rem = n - a * HW;
        cj  = rem / W;
        ci  = rem - cj * W;
        off_cell = (b * 255 + a * 85) * HW + rem;
        const float* cb = xp + off_cell;
        z0 = cb[0];
        z1 = cb[HW];
        z2 = cb[2 * HW];
        z3 = cb[3 * HW];
        z4 = cb[4 * HW];
    }

    if (tid == 0) s_npos = 0;
    if (tid < TT) {
        const float* g = gtb + ((long)b * TT + tid) * 4;
        float x1c = g[0], y1c = g[1], x2c = g[2], y2c = g[3];
        int valid = (x1c != -1.0f) || (y1c != -1.0f) || (x2c != -1.0f) || (y2c != -1.0f);
        float gw  = (x2c - x1c) * inv_stride;
        float gh  = (y2c - y1c) * inv_stride;
        float gxc = (x1c + x2c) * 0.5f * inv_stride;
        float gyc = (y1c + y2c) * 0.5f * inv_stride;
        int gi = min(max((int)gxc, 0), W - 1);   // trunc like astype(int32)
        int gj = min(max((int)gyc, 0), H - 1);
        float ax[3] = {a0x, a1x, a2x};
        float ay[3] = {a0y, a1y, a2y};
        int best = 0; float bestIoU = -1.0f;
        #pragma unroll
        for (int k = 0; k < 3; ++k) {
            float inter = fminf(gw, ax[k]) * fminf(gh, ay[k]);
            float iou = inter / (gw * gh + ax[k] * ay[k] - inter + 1e-16f);
            if (iou > bestIoU) { bestIoU = iou; best = k; }   // first max wins
        }
        s_flat[tid]  = best * HW + gj * W + gi;
        s_valid[tid] = valid;
        float tbx1 = x1c * inv_stride, tby1 = y1c * inv_stride;
        float tbx2 = x2c * inv_stride, tby2 = y2c * inv_stride;
        s_tb[tid][0] = tbx1; s_tb[tid][1] = tby1;
        s_tb[tid][2] = tbx2; s_tb[tid][3] = tby2;
        s_area[tid]  = (tbx2 - tbx1) * (tby2 - tby1);
        s_txy[tid][0] = gxc - (float)gi;
        s_txy[tid][1] = gyc - (float)gj;
        s_twh[tid][0] = logf(gw / ax[best] + 1e-16f);
        s_twh[tid][1] = logf(gh / ay[best] + 1e-16f);
        int lb = gtl[b * TT + tid];
        s_label[tid] = min(max(lb, 0), NCLS - 1);
    }
    __syncthreads();

    float loss = 0.0f;
    if (active) {
        float sax = (a == 0) ? a0x : (a == 1 ? a1x : a2x);
        float say = (a == 0) ? a0y : (a == 1 ? a1y : a2y);

        float px = sigmoidf_(z0);
        float py = sigmoidf_(z1);
        float bx = px + (float)ci;
        float by = py + (float)cj;
        float bw = expf(z2) * sax;
        float bh = expf(z3) * say;
        float pbx1 = bx - bw * 0.5f, pby1 = by - bh * 0.5f;
        float pbx2 = bx + bw * 0.5f, pby2 = by + bh * 0.5f;
        float area_p = (pbx2 - pbx1) * (pby2 - pby1);

        int L_ig = -1, L_pos = -1;
        #pragma unroll
        for (int t = 0; t < TT; ++t) {
            if (!s_valid[t]) continue;
            float ix1 = fmaxf(pbx1, s_tb[t][0]);
            float iy1 = fmaxf(pby1, s_tb[t][1]);
            float ix2 = fminf(pbx2, s_tb[t][2]);
            float iy2 = fminf(pby2, s_tb[t][3]);
            float inter = fmaxf(ix2 - ix1, 0.0f) * fmaxf(iy2 - iy1, 0.0f);
            float iou = inter / (area_p + s_area[t] - inter + 1e-16f);
            if (iou > 0.5f) L_ig = t;          // last ignoring target
            if (s_flat[t] == n) L_pos = t;     // last positive writer
        }

        bool pos = (L_pos >= 0) && (L_pos >= L_ig);  // positives win ties
        bool neg = !pos && (L_ig < 0);               // maskf == 0

        float pconf = sigmoidf_(z4);
        if (pos) {
            loss += bce_(pconf, 1.0f);                        // lambda_conf = 1
            float tx = s_txy[L_pos][0], ty = s_txy[L_pos][1];
            float tw = s_twh[L_pos][0], th = s_twh[L_pos][1];
            loss += 2.5f * (bce_(px, tx) + bce_(py, ty));     // lambda_xy
            float dw = z2 - tw, dh = z3 - th;
            loss += 2.5f * (dw * dw + dh * dh);               // lambda_wh
            unsigned int m0 = 0u, m1 = 0u, m2 = 0u;
            #pragma unroll
            for (int t = 0; t < TT; ++t) {
                if (s_valid[t] && s_flat[t] == n) {
                    int lb = s_label[t];
                    if      (lb < 32) m0 |= (1u << lb);
                    else if (lb < 64) m1 |= (1u << (lb - 32));
                    else              m2 |= (1u << (lb - 64));
                }
            }
            int slot = atomicAdd(&s_npos, 1);
            s_poff[slot] = off_cell;
            s_pm0[slot] = m0; s_pm1[slot] = m1; s_pm2[slot] = m2;
        } else if (neg) {
            loss += bce_(pconf, 0.0f);
        }
        // ignored cells (maskf == -1): no contribution
    }
    __syncthreads();

    // --- block-cooperative class loss: waves take worklist entries round-robin ---
    const int lane = tid & 63;
    const int wid  = tid >> 6;
    const int np = s_npos;
    for (int e = wid; e < np; e += 4) {
        int off_s = s_poff[e];
        unsigned int m0 = s_pm0[e], m1 = s_pm1[e], m2 = s_pm2[e];
        float za = xp[off_s + (5 + lane) * HW];                       // classes 0..63
        float zb = (lane < NCLS - 64) ? xp[off_s + (69 + lane) * HW]  // classes 64..79
                                      : 0.0f;
        int bita = (lane < 32) ? ((m0 >> lane) & 1) : ((m1 >> (lane - 32)) & 1);
        float contrib = bce_(sigmoidf_(za), (float)bita);
        if (lane < NCLS - 64) {
            int bitb = (m2 >> lane) & 1;
            contrib += bce_(sigmoidf_(zb), (float)bitb);
        }
        #pragma unroll
        for (int o = 32; o > 0; o >>= 1)
            contrib += __shfl_down(contrib, o, 64);
        if (lane == 0) loss += contrib;                       // lambda_cls = 1
    }

    // --- block reduction -> per-block partial ---
    #pragma unroll
    for (int o = 32; o > 0; o >>= 1)
        loss += __shfl_down(loss, o, 64);
    __shared__ float wsum[4];
    if (lane == 0) wsum[wid] = loss;
    __syncthreads();
    if (tid == 0) {
        float p = wsum[0] + wsum[1] + wsum[2] + wsum[3];
        // publish partial (agent scope), then bump the done-counter with release
        __hip_atomic_store(&partials[blk], p, __ATOMIC_RELAXED, __HIP_MEMORY_SCOPE_AGENT);
        int old = __hip_atomic_fetch_add(counter, 1, __ATOMIC_ACQ_REL, __HIP_MEMORY_SCOPE_AGENT);
        s_last = (old == nblocks - 1) ? 1 : 0;
    }
    __syncthreads();

    // --- last block performs the final reduction (deterministic) ---
    if (s_last) {
        float s = 0.0f;
        for (int i = tid; i < nblocks; i += 256)
            s += __hip_atomic_load(&partials[i], __ATOMIC_RELAXED, __HIP_MEMORY_SCOPE_AGENT);
        #pragma unroll
        for (int o = 32; o > 0; o >>= 1)
            s += __shfl_down(s, o, 64);
        __shared__ float fsum[4];
        if (lane == 0) fsum[wid] = s;
        __syncthreads();
        if (tid == 0)
            out[0] = (fsum[0] + fsum[1] + fsum[2] + fsum[3]) * inv_bs;
    }
}

extern "C" void kernel_launch(void* const* d_in, const int* in_sizes, int n_in,
                              void* d_out, int out_size, void* d_ws, size_t ws_size,
                              hipStream_t stream) {
    const float* x0  = (const float*)d_in[0];
    const float* x1  = (const float*)d_in[1];
    const float* x2  = (const float*)d_in[2];
    const float* gtb = (const float*)d_in[3];
    const int*   gtl = (const int*)d_in[4];
    float* out = (float*)d_out;

    const int bs = in_sizes[3] / (TT * 4);
    const int nblocks = 42 * bs;   // 2 + 8 + 32 blocks per batch
    const float inv_bs = 1.0f / (float)bs;

    float* partials = (float*)d_ws;
    int* counter = (int*)((char*)d_ws + (((size_t)nblocks * 4 + 255) / 256) * 256);

    hipMemsetAsync(counter, 0, sizeof(int), stream);
    yolo_fused_kernel<<<nblocks, 256, 0, stream>>>(
        x0, x1, x2, gtb, gtl, partials, counter, out, bs, nblocks, inv_bs);
}

// Round 5
// 150.228 us; speedup vs baseline: 1.2942x; 1.2942x over previous
//
#include <hip/hip_runtime.h>
#include <math.h>

#define TT 20
#define NCLS 80
#define MAXPOS 32   // positives per block <= targets per batch (20)

__device__ __forceinline__ float sigmoidf_(float z) {
    return 1.0f / (1.0f + expf(-z));
}

// torch BCELoss(reduction='none') on probabilities with log clamped at -100
__device__ __forceinline__ float bce_(float p, float t) {
    float logp   = fmaxf(logf(p), -100.0f);
    float log1mp = fmaxf(log1pf(-p), -100.0f);
    return -(t * logp + (1.0f - t) * log1mp);
}

// One fused dispatch over all 3 levels * bs batches.
// Block layout per batch: level0 (13x13): 2 blocks, level1 (26x26): 8, level2 (52x52): 32.
// NOTE: no global atomics anywhere — 1344 same-address device-scope atomics cost
// ~40 us on MI355X (measured R1 and R4). Per-block partials + tiny reduce kernel win.
__global__ __launch_bounds__(256) void yolo_fused_kernel(
    const float* __restrict__ x0, const float* __restrict__ x1, const float* __restrict__ x2,
    const float* __restrict__ gtb, const int* __restrict__ gtl,
    float* __restrict__ partials, int bs)
{
    const int tid = threadIdx.x;
    const int blk = blockIdx.x;
    const int t0 = 2 * bs, t1 = t0 + 8 * bs;

    int level, b, chunk, W;
    const float* __restrict__ xp;
    float inv_stride;
    if (blk < t0)      { level = 0; b = blk >> 1;        chunk = blk & 1;         xp = x0; W = 13; inv_stride = 1.0f / 32.0f; }
    else if (blk < t1) { level = 1; int r = blk - t0; b = r >> 3; chunk = r & 7;  xp = x1; W = 26; inv_stride = 1.0f / 16.0f; }
    else               { level = 2; int r = blk - t1; b = r >> 5; chunk = r & 31; xp = x2; W = 52; inv_stride = 1.0f / 8.0f;  }
    const int H = W, HW = W * W, cells = 3 * HW;

    float a0x = ((level == 0) ? 116.f : (level == 1) ? 30.f : 10.f) * inv_stride;
    float a0y = ((level == 0) ?  90.f : (level == 1) ? 61.f : 13.f) * inv_stride;
    float a1x = ((level == 0) ? 156.f : (level == 1) ? 62.f : 16.f) * inv_stride;
    float a1y = ((level == 0) ? 198.f : (level == 1) ? 45.f : 30.f) * inv_stride;
    float a2x = ((level == 0) ? 373.f : (level == 1) ? 59.f : 33.f) * inv_stride;
    float a2y = ((level == 0) ? 326.f : (level == 1) ? 119.f: 23.f) * inv_stride;

    __shared__ float s_tb[TT][4];
    __shared__ float s_area[TT];
    __shared__ float s_txy[TT][2];
    __shared__ float s_twh[TT][2];
    __shared__ int   s_flat[TT];
    __shared__ int   s_valid[TT];
    __shared__ int   s_label[TT];
    __shared__ int   s_npos;
    __shared__ int   s_poff[MAXPOS];
    __shared__ unsigned int s_pm0[MAXPOS], s_pm1[MAXPOS], s_pm2[MAXPOS];

    // ---- prefetch this thread's 5 channel values FIRST so the cold-HBM
    //      latency overlaps the target-prep phase and the barrier ----
    const int n = chunk * 256 + tid;
    const bool active = n < cells;
    int a = 0, rem = 0, ci = 0, cj = 0, off_cell = 0;
    float z0 = 0.f, z1 = 0.f, z2 = 0.f, z3 = 0.f, z4 = 0.f;
    if (active) {
        a   = n / HW;
        rem = n - a * HW;
        cj  = rem / W;
        ci  = rem - cj * W;
        off_cell = (b * 255 + a * 85) * HW + rem;
        const float* cb = xp + off_cell;
        z0 = cb[0];
        z1 = cb[HW];
        z2 = cb[2 * HW];
        z3 = cb[3 * HW];
        z4 = cb[4 * HW];
    }

    if (tid == 0) s_npos = 0;
    if (tid < TT) {
        const float* g = gtb + ((long)b * TT + tid) * 4;
        float x1c = g[0], y1c = g[1], x2c = g[2], y2c = g[3];
        int valid = (x1c != -1.0f) || (y1c != -1.0f) || (x2c != -1.0f) || (y2c != -1.0f);
        float gw  = (x2c - x1c) * inv_stride;
        float gh  = (y2c - y1c) * inv_stride;
        float gxc = (x1c + x2c) * 0.5f * inv_stride;
        float gyc = (y1c + y2c) * 0.5f * inv_stride;
        int gi = min(max((int)gxc, 0), W - 1);   // trunc like astype(int32)
        int gj = min(max((int)gyc, 0), H - 1);
        float ax[3] = {a0x, a1x, a2x};
        float ay[3] = {a0y, a1y, a2y};
        int best = 0; float bestIoU = -1.0f;
        #pragma unroll
        for (int k = 0; k < 3; ++k) {
            float inter = fminf(gw, ax[k]) * fminf(gh, ay[k]);
            float iou = inter / (gw * gh + ax[k] * ay[k] - inter + 1e-16f);
            if (iou > bestIoU) { bestIoU = iou; best = k; }   // first max wins
        }
        s_flat[tid]  = best * HW + gj * W + gi;
        s_valid[tid] = valid;
        float tbx1 = x1c * inv_stride, tby1 = y1c * inv_stride;
        float tbx2 = x2c * inv_stride, tby2 = y2c * inv_stride;
        s_tb[tid][0] = tbx1; s_tb[tid][1] = tby1;
        s_tb[tid][2] = tbx2; s_tb[tid][3] = tby2;
        s_area[tid]  = (tbx2 - tbx1) * (tby2 - tby1);
        s_txy[tid][0] = gxc - (float)gi;
        s_txy[tid][1] = gyc - (float)gj;
        s_twh[tid][0] = logf(gw / ax[best] + 1e-16f);
        s_twh[tid][1] = logf(gh / ay[best] + 1e-16f);
        int lb = gtl[b * TT + tid];
        s_label[tid] = min(max(lb, 0), NCLS - 1);
    }
    __syncthreads();

    float loss = 0.0f;
    if (active) {
        float sax = (a == 0) ? a0x : (a == 1 ? a1x : a2x);
        float say = (a == 0) ? a0y : (a == 1 ? a1y : a2y);

        float px = sigmoidf_(z0);
        float py = sigmoidf_(z1);
        float bx = px + (float)ci;
        float by = py + (float)cj;
        float bw = expf(z2) * sax;
        float bh = expf(z3) * say;
        float pbx1 = bx - bw * 0.5f, pby1 = by - bh * 0.5f;
        float pbx2 = bx + bw * 0.5f, pby2 = by + bh * 0.5f;
        float area_p = (pbx2 - pbx1) * (pby2 - pby1);

        int L_ig = -1, L_pos = -1;
        #pragma unroll
        for (int t = 0; t < TT; ++t) {
            if (!s_valid[t]) continue;
            float ix1 = fmaxf(pbx1, s_tb[t][0]);
            float iy1 = fmaxf(pby1, s_tb[t][1]);
            float ix2 = fminf(pbx2, s_tb[t][2]);
            float iy2 = fminf(pby2, s_tb[t][3]);
            float inter = fmaxf(ix2 - ix1, 0.0f) * fmaxf(iy2 - iy1, 0.0f);
            float iou = inter / (area_p + s_area[t] - inter + 1e-16f);
            if (iou > 0.5f) L_ig = t;          // last ignoring target
            if (s_flat[t] == n) L_pos = t;     // last positive writer
        }

        bool pos = (L_pos >= 0) && (L_pos >= L_ig);  // positives win ties
        bool neg = !pos && (L_ig < 0);               // maskf == 0

        float pconf = sigmoidf_(z4);
        if (pos) {
            loss += bce_(pconf, 1.0f);                        // lambda_conf = 1
            float tx = s_txy[L_pos][0], ty = s_txy[L_pos][1];
            float tw = s_twh[L_pos][0], th = s_twh[L_pos][1];
            loss += 2.5f * (bce_(px, tx) + bce_(py, ty));     // lambda_xy
            float dw = z2 - tw, dh = z3 - th;
            loss += 2.5f * (dw * dw + dh * dh);               // lambda_wh
            unsigned int m0 = 0u, m1 = 0u, m2 = 0u;
            #pragma unroll
            for (int t = 0; t < TT; ++t) {
                if (s_valid[t] && s_flat[t] == n) {
                    int lb = s_label[t];
                    if      (lb < 32) m0 |= (1u << lb);
                    else if (lb < 64) m1 |= (1u << (lb - 32));
                    else              m2 |= (1u << (lb - 64));
                }
            }
            int slot = atomicAdd(&s_npos, 1);   // LDS atomic only
            s_poff[slot] = off_cell;
            s_pm0[slot] = m0; s_pm1[slot] = m1; s_pm2[slot] = m2;
        } else if (neg) {
            loss += bce_(pconf, 0.0f);
        }
        // ignored cells (maskf == -1): no contribution
    }
    __syncthreads();

    // --- block-cooperative class loss: waves take worklist entries round-robin ---
    const int lane = tid & 63;
    const int wid  = tid >> 6;
    const int np = s_npos;
    for (int e = wid; e < np; e += 4) {
        int off_s = s_poff[e];
        unsigned int m0 = s_pm0[e], m1 = s_pm1[e], m2 = s_pm2[e];
        float za = xp[off_s + (5 + lane) * HW];                       // classes 0..63
        float zb = (lane < NCLS - 64) ? xp[off_s + (69 + lane) * HW]  // classes 64..79
                                      : 0.0f;
        int bita = (lane < 32) ? ((m0 >> lane) & 1) : ((m1 >> (lane - 32)) & 1);
        float contrib = bce_(sigmoidf_(za), (float)bita);
        if (lane < NCLS - 64) {
            int bitb = (m2 >> lane) & 1;
            contrib += bce_(sigmoidf_(zb), (float)bitb);
        }
        #pragma unroll
        for (int o = 32; o > 0; o >>= 1)
            contrib += __shfl_down(contrib, o, 64);
        if (lane == 0) loss += contrib;                       // lambda_cls = 1
    }

    // --- block reduction -> per-block partial (deterministic, no global atomics) ---
    #pragma unroll
    for (int o = 32; o > 0; o >>= 1)
        loss += __shfl_down(loss, o, 64);
    __shared__ float wsum[4];
    if (lane == 0) wsum[wid] = loss;
    __syncthreads();
    if (tid == 0)
        partials[blk] = wsum[0] + wsum[1] + wsum[2] + wsum[3];
}

__global__ __launch_bounds__(256) void yolo_reduce_kernel(
    const float* __restrict__ partials, float* __restrict__ out, int n, float inv_bs)
{
    const int tid = threadIdx.x;
    float s = 0.0f;
    for (int i = tid; i < n; i += 256) s += partials[i];
    #pragma unroll
    for (int o = 32; o > 0; o >>= 1)
        s += __shfl_down(s, o, 64);
    __shared__ float wsum[4];
    int lane = tid & 63, wid = tid >> 6;
    if (lane == 0) wsum[wid] = s;
    __syncthreads();
    if (tid == 0)
        out[0] = (wsum[0] + wsum[1] + wsum[2] + wsum[3]) * inv_bs;
}

extern "C" void kernel_launch(void* const* d_in, const int* in_sizes, int n_in,
                              void* d_out, int out_size, void* d_ws, size_t ws_size,
                              hipStream_t stream) {
    const float* x0  = (const float*)d_in[0];
    const float* x1  = (const float*)d_in[1];
    const float* x2  = (const float*)d_in[2];
    const float* gtb = (const float*)d_in[3];
    const int*   gtl = (const int*)d_in[4];
    float* out = (float*)d_out;
    float* partials = (float*)d_ws;

    const int bs = in_sizes[3] / (TT * 4);
    const int nblocks = 42 * bs;   // 2 + 8 + 32 blocks per batch
    const float inv_bs = 1.0f / (float)bs;

    yolo_fused_kernel<<<nblocks, 256, 0, stream>>>(x0, x1, x2, gtb, gtl, partials, bs);
    yolo_reduce_kernel<<<1, 256, 0, stream>>>(partials, out, nblocks, inv_bs);
}